// Round 10
// baseline (215.311 us; speedup 1.0000x reference)
//
#include <hip/hip_runtime.h>
#include <hip/hip_bf16.h>

// Problem constants
#define B_   2
#define N_   4096
#define DIM_ 768
#define H_   8
#define MROWS_ 8192   // B_*N_

typedef __bf16 bf16x8 __attribute__((ext_vector_type(8)));
typedef __bf16 bf16x4 __attribute__((ext_vector_type(4)));
typedef float  f32x4  __attribute__((ext_vector_type(4)));

static __device__ __forceinline__ f32x4 mfma16(bf16x8 a, bf16x8 b, f32x4 c) {
    return __builtin_amdgcn_mfma_f32_16x16x32_bf16(a, b, c, 0, 0, 0);
}

// async global->LDS, 16B per lane. LDS dst is wave-uniform base + lane*16.
#define GLDS16(g, l) \
    __builtin_amdgcn_global_load_lds((const __attribute__((address_space(1))) void*)(g), \
                                     (__attribute__((address_space(3))) void*)(l), 16, 0, 0)

// ---------------------------------------------------------------------------
// Kernel 1: x (fp32) -> xb (bf16), vectorized 4/thread
__global__ void cvt_x_kernel(const float* __restrict__ x, __bf16* __restrict__ xb, int n4) {
    int i = blockIdx.x * blockDim.x + threadIdx.x;
    if (i >= n4) return;
    float4 f = reinterpret_cast<const float4*>(x)[i];
    bf16x4 o;
    o[0] = (__bf16)f.x; o[1] = (__bf16)f.y; o[2] = (__bf16)f.z; o[3] = (__bf16)f.w;
    reinterpret_cast<bf16x4*>(xb)[i] = o;
}

// ---------------------------------------------------------------------------
// Kernel 2: LDS-tiled 64x64 transpose of weights -> bf16.
__global__ __launch_bounds__(256) void transpose_w_kernel(const float* __restrict__ Wq,
                                                          const float* __restrict__ Wk,
                                                          const float* __restrict__ Wv,
                                                          const float* __restrict__ Wo,
                                                          __bf16* __restrict__ wt,
                                                          __bf16* __restrict__ wot) {
    __shared__ float tile[64][65];
    const int bix = blockIdx.x;
    const float* src;
    int src_ld, rbase, cbase, dst_ld, drow, dcol;
    __bf16* dst;
    if (bix < 288) {                       // Wq/Wk/Wv: [768][512]
        int m = bix / 96, t = bix - m * 96;
        int tr = t >> 3, tc = t & 7;
        src = (m == 0) ? Wq : ((m == 1) ? Wk : Wv);
        src_ld = 512; rbase = tr * 64; cbase = tc * 64;
        dst = wt; dst_ld = 768; drow = m * 512 + tc * 64; dcol = tr * 64;
    } else {                               // Wo: [512][768]
        int t = bix - 288;
        int tr = t / 12, tc = t - tr * 12;
        src = Wo; src_ld = 768; rbase = tr * 64; cbase = tc * 64;
        dst = wot; dst_ld = 512; drow = tc * 64; dcol = tr * 64;
    }
#pragma unroll
    for (int kk = 0; kk < 4; ++kk) {
        int idx = threadIdx.x + kk * 256;
        int r = idx >> 4, c = (idx & 15) << 2;
        float4 f = *reinterpret_cast<const float4*>(&src[(size_t)(rbase + r) * src_ld + cbase + c]);
        tile[r][c] = f.x; tile[r][c + 1] = f.y; tile[r][c + 2] = f.z; tile[r][c + 3] = f.w;
    }
    __syncthreads();
#pragma unroll
    for (int kk = 0; kk < 4; ++kk) {
        int idx = threadIdx.x + kk * 256;
        int r = idx >> 4, c = (idx & 15) << 2;
        bf16x4 ov;
        ov[0] = (__bf16)tile[c][r];     ov[1] = (__bf16)tile[c + 1][r];
        ov[2] = (__bf16)tile[c + 2][r]; ov[3] = (__bf16)tile[c + 3][r];
        *reinterpret_cast<bf16x4*>(&dst[(size_t)(drow + r) * dst_ld + dcol + c]) = ov;
    }
}

// ---------------------------------------------------------------------------
// m97-structure GEMM main loop: 128x128 tile, BK=32, 4 waves (2x2 of 64x64),
// global_load_lds(16B) double-buffered staging, 2-phase pipeline.
template<int KSTEPS>
__device__ __forceinline__ void gemm_tile_main(const __bf16* __restrict__ A, const int lda,
                                               const int arow0,
                                               const __bf16* __restrict__ Bt, const int ldb,
                                               const int bcol0,
                                               __bf16* __restrict__ abuf,
                                               __bf16* __restrict__ bbuf,
                                               f32x4 (&acc)[4][4]) {
    const int lane = threadIdx.x & 63, wave = threadIdx.x >> 6;
    const int lr = lane & 15, lg = lane >> 4;
    const int wr = wave >> 1, wc = wave & 1;

    const int cid0 = wave * 128 + lane;
    const int cid1 = cid0 + 64;
    const __bf16* sA0 = A  + (size_t)(arow0 + (cid0 >> 2)) * lda + (cid0 & 3) * 8;
    const __bf16* sA1 = A  + (size_t)(arow0 + (cid1 >> 2)) * lda + (cid1 & 3) * 8;
    const __bf16* sB0 = Bt + (size_t)(bcol0 + (cid0 >> 2)) * ldb + (cid0 & 3) * 8;
    const __bf16* sB1 = Bt + (size_t)(bcol0 + (cid1 >> 2)) * ldb + (cid1 & 3) * 8;

    auto stage = [&](int buf, int ks) {
        __bf16* da = abuf + buf * 4096 + wave * 1024;
        __bf16* db = bbuf + buf * 4096 + wave * 1024;
        GLDS16(sA0 + ks * 32, da);
        GLDS16(sA1 + ks * 32, da + 512);
        GLDS16(sB0 + ks * 32, db);
        GLDS16(sB1 + ks * 32, db + 512);
    };

    stage(0, 0);
    asm volatile("s_waitcnt vmcnt(0)" ::: "memory");
    __syncthreads();

    const int ar_off = (wr * 64 + lr) * 32 + lg * 8;
    const int br_off = (wc * 64 + lr) * 32 + lg * 8;

    int buf = 0;
    for (int ks = 0; ks < KSTEPS; ++ks) {
        if (ks + 1 < KSTEPS) stage(buf ^ 1, ks + 1);
        const __bf16* ab = abuf + buf * 4096 + ar_off;
        const __bf16* bb = bbuf + buf * 4096 + br_off;
        bf16x8 af[4], bfr[4];
#pragma unroll
        for (int m = 0; m < 4; ++m) af[m] = *reinterpret_cast<const bf16x8*>(ab + m * 512);
#pragma unroll
        for (int n = 0; n < 4; ++n) bfr[n] = *reinterpret_cast<const bf16x8*>(bb + n * 512);
#pragma unroll
        for (int m = 0; m < 4; ++m)
#pragma unroll
            for (int n = 0; n < 4; ++n)
                acc[m][n] = mfma16(af[m], bfr[n], acc[m][n]);
        asm volatile("s_waitcnt vmcnt(0)" ::: "memory");
        __syncthreads();
        buf ^= 1;
    }
}

// ---------------------------------------------------------------------------
// Kernel 3: QKV projection GEMM. 768 blocks (XCD-chunked).
// Q pre-scaled by 0.125*log2(e) (attention uses exp2). V transposed [B,H,64,N].
__global__ __launch_bounds__(256) void qkv_gemm_kernel(const __bf16* __restrict__ xb,
                                                       const __bf16* __restrict__ wt,
                                                       __bf16* __restrict__ q,
                                                       __bf16* __restrict__ k,
                                                       __bf16* __restrict__ vt) {
    __shared__ __align__(16) __bf16 abuf[2 * 4096];
    __shared__ __align__(16) __bf16 bbuf[2 * 4096];

    const int bid = blockIdx.x;
    const int vb = (bid & 7) * 96 + (bid >> 3);
    const int by = vb % 12, bx = vb / 12;

    f32x4 acc[4][4] = {};
    gemm_tile_main<24>(xb, 768, bx * 128, wt, 768, by * 128, abuf, bbuf, acc);

    const int lane = threadIdx.x & 63, wave = threadIdx.x >> 6;
    const int lr = lane & 15, lg = lane >> 4;
    const int wr = wave >> 1, wc = wave & 1;
    const int bi = (bx * 128) >> 12;
    const int nbase = (bx * 128) & 4095;

    const float QSCALE = 0.125f * 1.44269504089f;   // fold log2(e): softmax uses exp2

#pragma unroll
    for (int n = 0; n < 4; ++n) {
        const int col0 = by * 128 + wc * 64 + n * 16;
        const int mtx = col0 >> 9;
        const int h   = (col0 >> 6) & 7;
        const int d0  = (col0 & 63) + lr;
        const size_t hb = (size_t)(bi * 8 + h);
#pragma unroll
        for (int m = 0; m < 4; ++m) {
            const int nn = nbase + wr * 64 + m * 16 + lg * 4;
            if (mtx == 0) {
#pragma unroll
                for (int r = 0; r < 4; ++r)
                    q[(hb * 4096 + nn + r) * 64 + d0] = (__bf16)(acc[m][n][r] * QSCALE);
            } else if (mtx == 1) {
#pragma unroll
                for (int r = 0; r < 4; ++r)
                    k[(hb * 4096 + nn + r) * 64 + d0] = (__bf16)acc[m][n][r];
            } else {
                bf16x4 ov;
#pragma unroll
                for (int r = 0; r < 4; ++r) ov[r] = (__bf16)acc[m][n][r];
                *reinterpret_cast<bf16x4*>(&vt[(hb * 64 + d0) * 4096 + nn]) = ov;
            }
        }
    }
}

// ---------------------------------------------------------------------------
// Kernel 4: split-K flash attention (round-7 structure, k-range halved).
// 1024 blocks = 4 blocks/CU = 4 waves/SIMD. Each block: 32 q-rows/wave x
// 32 k-tiles, emits un-normalized partial O (bf16, ob layout) + lsum (f32).
// P in-register via sigma-permuted K staging; lsum via ones-MFMA.
__global__ __launch_bounds__(256, 4) void attn_kernel(const __bf16* __restrict__ q,
                                                      const __bf16* __restrict__ k,
                                                      const __bf16* __restrict__ vt,
                                                      __bf16* __restrict__ part0,
                                                      __bf16* __restrict__ part1,
                                                      float* __restrict__ lsums) {
    const int lane = threadIdx.x & 63, wave = threadIdx.x >> 6;
    const int lr = lane & 15, lg = lane >> 4;

    const int bid  = blockIdx.x;
    const int vbid = (bid & 7) * 128 + (bid >> 3);   // 1024 % 8 == 0 -> bijective
    const int bh    = vbid >> 6;
    const int qs    = vbid & 63;
    const int qtile = qs >> 1;
    const int split = qs & 1;
    const int qbase = qtile * 128 + wave * 32;
    const int kt0   = split * 32;                     // this block's k-tile range

    const __bf16* Qh = q  + (size_t)bh * N_ * 64;
    const __bf16* Kh = k  + (size_t)bh * N_ * 64 + (size_t)kt0 * 4096;
    const __bf16* Vh = vt + (size_t)bh * 64 * N_ + kt0 * 64;

    __shared__ __align__(16) __bf16 kbuf[2][64][64];
    __shared__ __align__(16) __bf16 vbuf[2][64][64];

    const int l8 = lane >> 3, l7 = lane & 7;
    const int swz8 = (l7 ^ l8) * 8;

    // per-lane K source offsets: row sigma(i), chunk-swizzled (waves 0,1 stage K)
    int ksrc[4];
#pragma unroll
    for (int c = 0; c < 4; ++c) {
        int i = (wave & 1) * 32 + c * 8 + l8;
        int sig = ((i >> 4) & 1) * 32 + ((i >> 2) & 3) * 8 + ((i >> 5) & 1) * 4 + (i & 3);
        ksrc[c] = sig * 64 + swz8;
    }

    auto stageK = [&](int buf, int jt) {   // one K tile (waves 0,1), jt local
        if (wave < 2) {
            const __bf16* srcb = Kh + (size_t)jt * 4096;
            __bf16* dst = &kbuf[buf][(wave & 1) * 32][0];
#pragma unroll
            for (int c = 0; c < 4; ++c)
                GLDS16(srcb + ksrc[c], dst + c * 512);
        }
    };
    auto stageV = [&](int buf, int jt) {   // one V tile (waves 2,3), jt local
        if (wave >= 2) {
            const int w2 = wave - 2;
            const __bf16* src = Vh + (size_t)(w2 * 32 + l8) * 4096 + jt * 64 + swz8;
            __bf16* dst = &vbuf[buf][w2 * 32][0];
#pragma unroll
            for (int c = 0; c < 4; ++c)
                GLDS16(src + (size_t)c * 8 * 4096, dst + c * 512);
        }
    };

    bf16x8 qf[2][2];
#pragma unroll
    for (int frag = 0; frag < 2; ++frag)
#pragma unroll
        for (int kc = 0; kc < 2; ++kc)
            qf[frag][kc] = *reinterpret_cast<const bf16x8*>(
                Qh + (size_t)(qbase + frag * 16 + lr) * 64 + kc * 32 + lg * 8);

    f32x4 acc[2][4] = {};
    f32x4 accl[2] = {};
    bf16x8 vones;
#pragma unroll
    for (int t = 0; t < 8; ++t) vones[t] = (__bf16)1.0f;

    auto QK = [&](f32x4 (&s)[2][4], const __bf16* kb_) {
        const char* kb = (const char*)kb_;
        __builtin_amdgcn_s_setprio(1);
#pragma unroll
        for (int kc = 0; kc < 2; ++kc) {
#pragma unroll
            for (int cb = 0; cb < 4; ++cb) {
                const int row = cb * 16 + lr;
                bf16x8 bk = *reinterpret_cast<const bf16x8*>(
                    kb + row * 128 + (((kc * 4 + lg) ^ (lr & 7)) << 4));
                if (kc == 0) { s[0][cb] = mfma16(bk, qf[0][0], {}); s[1][cb] = mfma16(bk, qf[1][0], {}); }
                else         { s[0][cb] = mfma16(bk, qf[0][1], s[0][cb]); s[1][cb] = mfma16(bk, qf[1][1], s[1][cb]); }
            }
        }
        __builtin_amdgcn_s_setprio(0);
    };
    auto EXP = [&](f32x4 (&s)[2][4], bf16x8 (&pk)[2][2]) {
#pragma unroll
        for (int frag = 0; frag < 2; ++frag)
#pragma unroll
            for (int kc = 0; kc < 2; ++kc) {
#pragma unroll
                for (int t = 0; t < 8; ++t)
                    pk[frag][kc][t] = (__bf16)__builtin_amdgcn_exp2f(s[frag][kc + 2 * (t >> 2)][t & 3]);
                accl[frag] = mfma16(pk[frag][kc], vones, accl[frag]);   // lsum via matrix pipe
            }
    };
    auto PV = [&](bf16x8 (&pk)[2][2], const __bf16* vb_) {
        const char* vb = (const char*)vb_;
        __builtin_amdgcn_s_setprio(1);
#pragma unroll
        for (int kc = 0; kc < 2; ++kc) {
#pragma unroll
            for (int cbv = 0; cbv < 4; ++cbv) {
                const int row = cbv * 16 + lr;
                bf16x8 bv = *reinterpret_cast<const bf16x8*>(
                    vb + row * 128 + (((kc * 4 + lg) ^ (lr & 7)) << 4));
                acc[0][cbv] = mfma16(pk[0][kc], bv, acc[0][cbv]);
                acc[1][cbv] = mfma16(pk[1][kc], bv, acc[1][cbv]);
            }
        }
        __builtin_amdgcn_s_setprio(0);
    };

    f32x4 sA[2][4], sB[2][4];
    bf16x8 pkA[2][2], pkB[2][2];

    // ---- prologue
    stageK(0, 0);
    asm volatile("s_waitcnt vmcnt(0)" ::: "memory");
    __syncthreads();

    stageK(1, 1);
    stageV(0, 0);
    QK(sA, &kbuf[0][0][0]);
    asm volatile("s_waitcnt vmcnt(0)" ::: "memory");
    __syncthreads();

    // ---- main loop: pairs (jt odd, jt even), jt = 1..30 local
    for (int t = 0; t < 15; ++t) {
        const int jt = 2 * t + 1;
        stageK(0, jt + 1);
        stageV(1, jt);
        EXP(sA, pkA);
        QK(sB, &kbuf[1][0][0]);
        PV(pkA, &vbuf[0][0][0]);
        asm volatile("s_waitcnt vmcnt(0)" ::: "memory");
        __syncthreads();
        stageK(1, jt + 2);
        stageV(0, jt + 1);
        EXP(sB, pkB);
        QK(sA, &kbuf[0][0][0]);
        PV(pkB, &vbuf[1][0][0]);
        asm volatile("s_waitcnt vmcnt(0)" ::: "memory");
        __syncthreads();
    }

    // ---- jt = 31 (final): no more K; finish tile 30, QK(31)
    stageV(1, 31);
    EXP(sA, pkA);
    QK(sB, &kbuf[1][0][0]);
    PV(pkA, &vbuf[0][0][0]);
    asm volatile("s_waitcnt vmcnt(0)" ::: "memory");
    __syncthreads();

    // ---- epilogue: finish tile 31
    EXP(sB, pkB);
    PV(pkB, &vbuf[1][0][0]);

    // write un-normalized partials (ob layout) + lsum
    __bf16* po = split ? part1 : part0;
    float*  ls = lsums + (size_t)split * 65536;
    const int b = bh >> 3, h = bh & 7;
#pragma unroll
    for (int frag = 0; frag < 2; ++frag) {
#pragma unroll
        for (int r = 0; r < 4; ++r) {
            const int qrow = qbase + frag * 16 + lg * 4 + r;
            const int row = b * N_ + qrow;
#pragma unroll
            for (int cbv = 0; cbv < 4; ++cbv)
                po[(size_t)row * 512 + h * 64 + cbv * 16 + lr] = (__bf16)acc[frag][cbv][r];
            if (lr == 0)
                ls[bh * 4096 + qrow] = accl[frag][r];
        }
    }
}

// ---------------------------------------------------------------------------
// Kernel 4b: combine split-K partials: ob = (p0 + p1) / (l0 + l1), in-place
// into p0. Same-index elementwise -> race-free. 8 bf16 per thread.
__global__ __launch_bounds__(256) void combine_kernel(__bf16* __restrict__ p0,
                                                      const __bf16* __restrict__ p1,
                                                      const float* __restrict__ lsums) {
    const int g = blockIdx.x * 256 + threadIdx.x;     // [0, 524288)
    const int row = g >> 6;                            // [0, 8192)
    const int col8 = g & 63;                           // 8-elem chunk within 512
    const int h = col8 >> 3;
    const int b = row >> 12;
    const int qr = row & 4095;
    const int bhq = (b * 8 + h) * 4096 + qr;
    const float l = lsums[bhq] + lsums[65536 + bhq];
    const float inv = 1.f / l;

    const size_t off = (size_t)row * 512 + col8 * 8;
    bf16x8 a0 = *reinterpret_cast<const bf16x8*>(p0 + off);
    bf16x8 a1 = *reinterpret_cast<const bf16x8*>(p1 + off);
    bf16x8 ov;
#pragma unroll
    for (int t = 0; t < 8; ++t)
        ov[t] = (__bf16)(((float)a0[t] + (float)a1[t]) * inv);
    *reinterpret_cast<bf16x8*>(p0 + off) = ov;
}

// ---------------------------------------------------------------------------
// Kernel 5: output projection GEMM. 384 blocks. K=512.
__global__ __launch_bounds__(256) void out_gemm_kernel(const __bf16* __restrict__ ob,
                                                       const __bf16* __restrict__ wot,
                                                       const float* __restrict__ bo,
                                                       float* __restrict__ out) {
    __shared__ __align__(16) __bf16 abuf[2 * 4096];
    __shared__ __align__(16) __bf16 bbuf[2 * 4096];

    const int bid = blockIdx.x;
    const int vb = (bid & 7) * 48 + (bid >> 3);
    const int by = vb % 6, bx = vb / 6;

    f32x4 acc[4][4] = {};
    gemm_tile_main<16>(ob, 512, bx * 128, wot, 512, by * 128, abuf, bbuf, acc);

    const int lane = threadIdx.x & 63, wave = threadIdx.x >> 6;
    const int lr = lane & 15, lg = lane >> 4;
    const int wr = wave >> 1, wc = wave & 1;

#pragma unroll
    for (int n = 0; n < 4; ++n) {
        const int col = by * 128 + wc * 64 + n * 16 + lr;
        const float bias = bo[col];
#pragma unroll
        for (int m = 0; m < 4; ++m) {
            const int row0 = bx * 128 + wr * 64 + m * 16 + lg * 4;
#pragma unroll
            for (int r = 0; r < 4; ++r)
                out[(size_t)(row0 + r) * 768 + col] = acc[m][n][r] + bias;
        }
    }
}

// ---------------------------------------------------------------------------
extern "C" void kernel_launch(void* const* d_in, const int* in_sizes, int n_in,
                              void* d_out, int out_size, void* d_ws, size_t ws_size,
                              hipStream_t stream) {
    const float* x  = (const float*)d_in[0];
    const float* Wq = (const float*)d_in[1];
    const float* Wk = (const float*)d_in[2];
    const float* Wv = (const float*)d_in[3];
    const float* Wo = (const float*)d_in[4];
    const float* bo = (const float*)d_in[5];
    float* out = (float*)d_out;

    char* ws = (char*)d_ws;
    __bf16* xb  = (__bf16*)(ws);                                  // 12,582,912 (dead after qkv)
    __bf16* wt  = (__bf16*)(ws + 12582912);                       //  2,359,296
    __bf16* wot = (__bf16*)(ws + 12582912 + 2359296);             //    786,432
    char*   p0  = ws + 12582912 + 2359296 + 786432;               // 15,728,640
    __bf16* qw  = (__bf16*)(p0);                                  //  8,388,608
    __bf16* kw  = (__bf16*)(p0 + 8388608);
    __bf16* vtw = (__bf16*)(p0 + 2 * (size_t)8388608);
    __bf16* obf = (__bf16*)(p0 + 3 * (size_t)8388608);            // = part0
    // split-K partials reuse the xb region (attn runs after qkv_gemm):
    __bf16* part1 = (__bf16*)(ws);                                //  8,388,608
    float*  lsums = (float*)(ws + 8388608);                       //    524,288
    // total ws use: 49,283,072 bytes

    cvt_x_kernel<<<6144, 256, 0, stream>>>(x, xb, MROWS_ * DIM_ / 4);
    transpose_w_kernel<<<384, 256, 0, stream>>>(Wq, Wk, Wv, Wo, wt, wot);
    qkv_gemm_kernel<<<dim3(768), 256, 0, stream>>>(xb, wt, qw, kw, vtw);
    attn_kernel<<<1024, 256, 0, stream>>>(qw, kw, vtw, obf, part1, lsums);
    combine_kernel<<<2048, 256, 0, stream>>>(obf, part1, lsums);
    out_gemm_kernel<<<384, 256, 0, stream>>>(obf, wot, bo, out);
}

// Round 11
// 127.836 us; speedup vs baseline: 1.6843x; 1.6843x over previous
//
#include <hip/hip_runtime.h>
#include <hip/hip_bf16.h>

// Problem constants
#define B_   2
#define N_   4096
#define DIM_ 768
#define H_   8
#define MROWS_ 8192   // B_*N_

typedef __bf16 bf16x8 __attribute__((ext_vector_type(8)));
typedef __bf16 bf16x4 __attribute__((ext_vector_type(4)));
typedef float  f32x4  __attribute__((ext_vector_type(4)));

static __device__ __forceinline__ f32x4 mfma16(bf16x8 a, bf16x8 b, f32x4 c) {
    return __builtin_amdgcn_mfma_f32_16x16x32_bf16(a, b, c, 0, 0, 0);
}

// async global->LDS, 16B per lane. LDS dst is wave-uniform base + lane*16.
#define GLDS16(g, l) \
    __builtin_amdgcn_global_load_lds((const __attribute__((address_space(1))) void*)(g), \
                                     (__attribute__((address_space(3))) void*)(l), 16, 0, 0)

// ---------------------------------------------------------------------------
// Kernel 1: x (fp32) -> xb (bf16), vectorized 4/thread
__global__ void cvt_x_kernel(const float* __restrict__ x, __bf16* __restrict__ xb, int n4) {
    int i = blockIdx.x * blockDim.x + threadIdx.x;
    if (i >= n4) return;
    float4 f = reinterpret_cast<const float4*>(x)[i];
    bf16x4 o;
    o[0] = (__bf16)f.x; o[1] = (__bf16)f.y; o[2] = (__bf16)f.z; o[3] = (__bf16)f.w;
    reinterpret_cast<bf16x4*>(xb)[i] = o;
}

// ---------------------------------------------------------------------------
// Kernel 2: LDS-tiled 64x64 transpose of weights -> bf16.
__global__ __launch_bounds__(256) void transpose_w_kernel(const float* __restrict__ Wq,
                                                          const float* __restrict__ Wk,
                                                          const float* __restrict__ Wv,
                                                          const float* __restrict__ Wo,
                                                          __bf16* __restrict__ wt,
                                                          __bf16* __restrict__ wot) {
    __shared__ float tile[64][65];
    const int bix = blockIdx.x;
    const float* src;
    int src_ld, rbase, cbase, dst_ld, drow, dcol;
    __bf16* dst;
    if (bix < 288) {                       // Wq/Wk/Wv: [768][512]
        int m = bix / 96, t = bix - m * 96;
        int tr = t >> 3, tc = t & 7;
        src = (m == 0) ? Wq : ((m == 1) ? Wk : Wv);
        src_ld = 512; rbase = tr * 64; cbase = tc * 64;
        dst = wt; dst_ld = 768; drow = m * 512 + tc * 64; dcol = tr * 64;
    } else {                               // Wo: [512][768]
        int t = bix - 288;
        int tr = t / 12, tc = t - tr * 12;
        src = Wo; src_ld = 768; rbase = tr * 64; cbase = tc * 64;
        dst = wot; dst_ld = 512; drow = tc * 64; dcol = tr * 64;
    }
#pragma unroll
    for (int kk = 0; kk < 4; ++kk) {
        int idx = threadIdx.x + kk * 256;
        int r = idx >> 4, c = (idx & 15) << 2;
        float4 f = *reinterpret_cast<const float4*>(&src[(size_t)(rbase + r) * src_ld + cbase + c]);
        tile[r][c] = f.x; tile[r][c + 1] = f.y; tile[r][c + 2] = f.z; tile[r][c + 3] = f.w;
    }
    __syncthreads();
#pragma unroll
    for (int kk = 0; kk < 4; ++kk) {
        int idx = threadIdx.x + kk * 256;
        int r = idx >> 4, c = (idx & 15) << 2;
        bf16x4 ov;
        ov[0] = (__bf16)tile[c][r];     ov[1] = (__bf16)tile[c + 1][r];
        ov[2] = (__bf16)tile[c + 2][r]; ov[3] = (__bf16)tile[c + 3][r];
        *reinterpret_cast<bf16x4*>(&dst[(size_t)(drow + r) * dst_ld + dcol + c]) = ov;
    }
}

// ---------------------------------------------------------------------------
// m97-structure GEMM main loop: 128x128 tile, BK=32, 4 waves (2x2 of 64x64),
// global_load_lds(16B) double-buffered staging, 2-phase pipeline.
template<int KSTEPS>
__device__ __forceinline__ void gemm_tile_main(const __bf16* __restrict__ A, const int lda,
                                               const int arow0,
                                               const __bf16* __restrict__ Bt, const int ldb,
                                               const int bcol0,
                                               __bf16* __restrict__ abuf,
                                               __bf16* __restrict__ bbuf,
                                               f32x4 (&acc)[4][4]) {
    const int lane = threadIdx.x & 63, wave = threadIdx.x >> 6;
    const int lr = lane & 15, lg = lane >> 4;
    const int wr = wave >> 1, wc = wave & 1;

    const int cid0 = wave * 128 + lane;
    const int cid1 = cid0 + 64;
    const __bf16* sA0 = A  + (size_t)(arow0 + (cid0 >> 2)) * lda + (cid0 & 3) * 8;
    const __bf16* sA1 = A  + (size_t)(arow0 + (cid1 >> 2)) * lda + (cid1 & 3) * 8;
    const __bf16* sB0 = Bt + (size_t)(bcol0 + (cid0 >> 2)) * ldb + (cid0 & 3) * 8;
    const __bf16* sB1 = Bt + (size_t)(bcol0 + (cid1 >> 2)) * ldb + (cid1 & 3) * 8;

    auto stage = [&](int buf, int ks) {
        __bf16* da = abuf + buf * 4096 + wave * 1024;
        __bf16* db = bbuf + buf * 4096 + wave * 1024;
        GLDS16(sA0 + ks * 32, da);
        GLDS16(sA1 + ks * 32, da + 512);
        GLDS16(sB0 + ks * 32, db);
        GLDS16(sB1 + ks * 32, db + 512);
    };

    stage(0, 0);
    asm volatile("s_waitcnt vmcnt(0)" ::: "memory");
    __syncthreads();

    const int ar_off = (wr * 64 + lr) * 32 + lg * 8;
    const int br_off = (wc * 64 + lr) * 32 + lg * 8;

    int buf = 0;
    for (int ks = 0; ks < KSTEPS; ++ks) {
        if (ks + 1 < KSTEPS) stage(buf ^ 1, ks + 1);
        const __bf16* ab = abuf + buf * 4096 + ar_off;
        const __bf16* bb = bbuf + buf * 4096 + br_off;
        bf16x8 af[4], bfr[4];
#pragma unroll
        for (int m = 0; m < 4; ++m) af[m] = *reinterpret_cast<const bf16x8*>(ab + m * 512);
#pragma unroll
        for (int n = 0; n < 4; ++n) bfr[n] = *reinterpret_cast<const bf16x8*>(bb + n * 512);
#pragma unroll
        for (int m = 0; m < 4; ++m)
#pragma unroll
            for (int n = 0; n < 4; ++n)
                acc[m][n] = mfma16(af[m], bfr[n], acc[m][n]);
        asm volatile("s_waitcnt vmcnt(0)" ::: "memory");
        __syncthreads();
        buf ^= 1;
    }
}

// ---------------------------------------------------------------------------
// Kernel 3: QKV projection GEMM. 768 blocks (XCD-chunked).
// Q pre-scaled by 0.125*log2(e) (attention uses exp2). V transposed [B,H,64,N].
__global__ __launch_bounds__(256) void qkv_gemm_kernel(const __bf16* __restrict__ xb,
                                                       const __bf16* __restrict__ wt,
                                                       __bf16* __restrict__ q,
                                                       __bf16* __restrict__ k,
                                                       __bf16* __restrict__ vt) {
    __shared__ __align__(16) __bf16 abuf[2 * 4096];
    __shared__ __align__(16) __bf16 bbuf[2 * 4096];

    const int bid = blockIdx.x;
    const int vb = (bid & 7) * 96 + (bid >> 3);
    const int by = vb % 12, bx = vb / 12;

    f32x4 acc[4][4] = {};
    gemm_tile_main<24>(xb, 768, bx * 128, wt, 768, by * 128, abuf, bbuf, acc);

    const int lane = threadIdx.x & 63, wave = threadIdx.x >> 6;
    const int lr = lane & 15, lg = lane >> 4;
    const int wr = wave >> 1, wc = wave & 1;
    const int bi = (bx * 128) >> 12;
    const int nbase = (bx * 128) & 4095;

    const float QSCALE = 0.125f * 1.44269504089f;   // fold log2(e): softmax uses exp2

#pragma unroll
    for (int n = 0; n < 4; ++n) {
        const int col0 = by * 128 + wc * 64 + n * 16;
        const int mtx = col0 >> 9;
        const int h   = (col0 >> 6) & 7;
        const int d0  = (col0 & 63) + lr;
        const size_t hb = (size_t)(bi * 8 + h);
#pragma unroll
        for (int m = 0; m < 4; ++m) {
            const int nn = nbase + wr * 64 + m * 16 + lg * 4;
            if (mtx == 0) {
#pragma unroll
                for (int r = 0; r < 4; ++r)
                    q[(hb * 4096 + nn + r) * 64 + d0] = (__bf16)(acc[m][n][r] * QSCALE);
            } else if (mtx == 1) {
#pragma unroll
                for (int r = 0; r < 4; ++r)
                    k[(hb * 4096 + nn + r) * 64 + d0] = (__bf16)acc[m][n][r];
            } else {
                bf16x4 ov;
#pragma unroll
                for (int r = 0; r < 4; ++r) ov[r] = (__bf16)acc[m][n][r];
                *reinterpret_cast<bf16x4*>(&vt[(hb * 64 + d0) * 4096 + nn]) = ov;
            }
        }
    }
}

// ---------------------------------------------------------------------------
// Kernel 4: flash attention, LDS-local split-K across waves.
// 512 blocks (XCD-chunked), 4 waves. Wave (qg=w>>1, kh=w&1) computes
// 64 q-rows x 32 k-cols per tile -> per-wave LDS reads halved (4 bk + 4 bv).
// sigma-permuted K staging keeps P in-register; wave kh reads s-slot groups
// {kh, kh+2} so pk[t] = P[q][k = kh*32 + lg*8 + t] matches V chunk kc=kh.
// End: kh=1 waves pass partial acc (bf16) + lsum (f32) via LDS; kh=0 combines.
__global__ __launch_bounds__(256) void attn_kernel(const __bf16* __restrict__ q,
                                                   const __bf16* __restrict__ k,
                                                   const __bf16* __restrict__ vt,
                                                   __bf16* __restrict__ o) {
    const int lane = threadIdx.x & 63, wave = threadIdx.x >> 6;
    const int lr = lane & 15, lg = lane >> 4;
    const int qg = wave >> 1, kh = wave & 1;

    const int bid  = blockIdx.x;
    const int vbid = (bid & 7) * 64 + (bid >> 3);
    const int qtile = vbid & 31;
    const int bh    = vbid >> 5;
    const int qbase = qtile * 128 + qg * 64;

    const __bf16* Qh = q  + (size_t)bh * N_ * 64;
    const __bf16* Kh = k  + (size_t)bh * N_ * 64;
    const __bf16* Vh = vt + (size_t)bh * 64 * N_;

    __shared__ __align__(16) char smem[32768];
    __bf16* kb0 = (__bf16*)smem;            // kbuf[2][64][64], 16KB
    __bf16* vb0 = (__bf16*)(smem + 16384);  // vbuf[2][64][64], 16KB

    const int l8 = lane >> 3, l7 = lane & 7;
    const int swz8 = (l7 ^ l8) * 8;

    // per-lane K source offsets: row sigma(i), chunk-swizzled (waves 0,1 stage K)
    int ksrc[4];
#pragma unroll
    for (int c = 0; c < 4; ++c) {
        int i = (wave & 1) * 32 + c * 8 + l8;
        int sig = ((i >> 4) & 1) * 32 + ((i >> 2) & 3) * 8 + ((i >> 5) & 1) * 4 + (i & 3);
        ksrc[c] = sig * 64 + swz8;
    }

    auto stageK = [&](int buf, int jt) {    // one K tile (waves 0,1)
        if (wave < 2) {
            const __bf16* srcb = Kh + (size_t)jt * 4096;
            __bf16* dst = kb0 + buf * 4096 + (wave & 1) * 2048;
#pragma unroll
            for (int c = 0; c < 4; ++c)
                GLDS16(srcb + ksrc[c], dst + c * 512);
        }
    };
    auto stageV = [&](int buf, int jt) {    // one V tile (waves 2,3)
        if (wave >= 2) {
            const int w2 = wave - 2;
            const __bf16* src = Vh + (size_t)(w2 * 32 + l8) * 4096 + jt * 64 + swz8;
            __bf16* dst = vb0 + buf * 4096 + w2 * 2048;
#pragma unroll
            for (int c = 0; c < 4; ++c)
                GLDS16(src + (size_t)c * 8 * 4096, dst + c * 512);
        }
    };

    bf16x8 qf[4][2];
#pragma unroll
    for (int f = 0; f < 4; ++f)
#pragma unroll
        for (int kc = 0; kc < 2; ++kc)
            qf[f][kc] = *reinterpret_cast<const bf16x8*>(
                Qh + (size_t)(qbase + f * 16 + lr) * 64 + kc * 32 + lg * 8);

    f32x4 acc[4][4] = {};
    f32x4 accl[4] = {};
    bf16x8 vones;
#pragma unroll
    for (int t = 0; t < 8; ++t) vones[t] = (__bf16)1.0f;

    f32x4 s[4][2];      // 64q x 32k logits (s-slot groups kh, kh+2)
    bf16x8 pk[4];       // previous tile's P, PV A-fragments

    auto QK = [&](const __bf16* kb_) {
        const char* kb = (const char*)kb_;
        __builtin_amdgcn_s_setprio(1);
#pragma unroll
        for (int kc = 0; kc < 2; ++kc) {
#pragma unroll
            for (int c2 = 0; c2 < 2; ++c2) {
                const int row = (kh + 2 * c2) * 16 + lr;
                bf16x8 bk = *reinterpret_cast<const bf16x8*>(
                    kb + row * 128 + (((kc * 4 + lg) ^ (lr & 7)) << 4));
#pragma unroll
                for (int f = 0; f < 4; ++f) {
                    if (kc == 0) s[f][c2] = mfma16(bk, qf[f][0], {});
                    else         s[f][c2] = mfma16(bk, qf[f][1], s[f][c2]);
                }
            }
        }
        __builtin_amdgcn_s_setprio(0);
    };
    auto EXP = [&]() {   // s -> pk; partial lsum via matrix pipe
#pragma unroll
        for (int f = 0; f < 4; ++f) {
#pragma unroll
            for (int t = 0; t < 8; ++t)
                pk[f][t] = (__bf16)__builtin_amdgcn_exp2f(s[f][t >> 2][t & 3]);
            accl[f] = mfma16(pk[f], vones, accl[f]);
        }
    };
    auto PV = [&](const __bf16* vb_) {   // consumes pk; V chunk kc = kh
        const char* vb = (const char*)vb_;
        __builtin_amdgcn_s_setprio(1);
#pragma unroll
        for (int cbv = 0; cbv < 4; ++cbv) {
            const int row = cbv * 16 + lr;
            bf16x8 bv = *reinterpret_cast<const bf16x8*>(
                vb + row * 128 + (((kh * 4 + lg) ^ (lr & 7)) << 4));
#pragma unroll
            for (int f = 0; f < 4; ++f)
                acc[f][cbv] = mfma16(pk[f], bv, acc[f][cbv]);
        }
        __builtin_amdgcn_s_setprio(0);
    };

    // ---- prologue
    stageK(0, 0);
    asm volatile("s_waitcnt vmcnt(0)" ::: "memory");
    __syncthreads();

    // ---- iter 0
    stageK(1, 1);
    stageV(0, 0);
    QK(kb0);             // tile 0 from kbuf[0]
    EXP();               // pk = P(0)
    asm volatile("s_waitcnt vmcnt(0)" ::: "memory");
    __syncthreads();

    // ---- iters 1..62
    for (int jt = 1; jt < 63; ++jt) {
        stageK((jt + 1) & 1, jt + 1);
        stageV(jt & 1, jt);
        QK(kb0 + (jt & 1) * 4096);          // tile jt
        PV(vb0 + ((jt - 1) & 1) * 4096);    // tile jt-1
        EXP();                              // pk = P(jt)
        asm volatile("s_waitcnt vmcnt(0)" ::: "memory");
        __syncthreads();
    }

    // ---- iter 63 (no more K)
    stageV(1, 63);
    QK(kb0 + 4096);      // tile 63 from kbuf[1]
    PV(vb0);             // tile 62 from vbuf[0]
    EXP();               // pk = P(63)
    asm volatile("s_waitcnt vmcnt(0)" ::: "memory");
    __syncthreads();

    // ---- final PV(63) from vbuf[1]
    PV(vb0 + 4096);
    __syncthreads();     // all waves done reading K/V tiles

    // ---- cross-wave combine: kh=1 writes partials (acc bf16, lsum f32) to LDS
    char* ex = smem + qg * 13824;
    if (kh == 1) {
#pragma unroll
        for (int f = 0; f < 4; ++f) {
#pragma unroll
            for (int cbv = 0; cbv < 4; ++cbv) {
                bf16x4 p4;
#pragma unroll
                for (int r = 0; r < 4; ++r) p4[r] = (__bf16)acc[f][cbv][r];
                *reinterpret_cast<bf16x4*>(ex + lane * 136 + (f * 4 + cbv) * 8) = p4;
            }
            *reinterpret_cast<f32x4*>(ex + 8704 + lane * 80 + f * 16) = accl[f];
        }
    }
    __syncthreads();

    if (kh == 0) {
        const int b = bh >> 3, h = bh & 7;
#pragma unroll
        for (int f = 0; f < 4; ++f) {
            f32x4 lp = *reinterpret_cast<const f32x4*>(ex + 8704 + lane * 80 + f * 16);
            f32x4 inv;
#pragma unroll
            for (int r = 0; r < 4; ++r) inv[r] = 1.f / (accl[f][r] + lp[r]);
#pragma unroll
            for (int cbv = 0; cbv < 4; ++cbv) {
                bf16x4 ap = *reinterpret_cast<const bf16x4*>(ex + lane * 136 + (f * 4 + cbv) * 8);
#pragma unroll
                for (int r = 0; r < 4; ++r) {
                    const int row = b * N_ + qbase + f * 16 + lg * 4 + r;
                    o[(size_t)row * 512 + h * 64 + cbv * 16 + lr] =
                        (__bf16)((acc[f][cbv][r] + (float)ap[r]) * inv[r]);
                }
            }
        }
    }
}

// ---------------------------------------------------------------------------
// Kernel 5: output projection GEMM. 384 blocks. K=512.
__global__ __launch_bounds__(256) void out_gemm_kernel(const __bf16* __restrict__ ob,
                                                       const __bf16* __restrict__ wot,
                                                       const float* __restrict__ bo,
                                                       float* __restrict__ out) {
    __shared__ __align__(16) __bf16 abuf[2 * 4096];
    __shared__ __align__(16) __bf16 bbuf[2 * 4096];

    const int bid = blockIdx.x;
    const int vb = (bid & 7) * 48 + (bid >> 3);
    const int by = vb % 6, bx = vb / 6;

    f32x4 acc[4][4] = {};
    gemm_tile_main<16>(ob, 512, bx * 128, wot, 512, by * 128, abuf, bbuf, acc);

    const int lane = threadIdx.x & 63, wave = threadIdx.x >> 6;
    const int lr = lane & 15, lg = lane >> 4;
    const int wr = wave >> 1, wc = wave & 1;

#pragma unroll
    for (int n = 0; n < 4; ++n) {
        const int col = by * 128 + wc * 64 + n * 16 + lr;
        const float bias = bo[col];
#pragma unroll
        for (int m = 0; m < 4; ++m) {
            const int row0 = bx * 128 + wr * 64 + m * 16 + lg * 4;
#pragma unroll
            for (int r = 0; r < 4; ++r)
                out[(size_t)(row0 + r) * 768 + col] = acc[m][n][r] + bias;
        }
    }
}

// ---------------------------------------------------------------------------
extern "C" void kernel_launch(void* const* d_in, const int* in_sizes, int n_in,
                              void* d_out, int out_size, void* d_ws, size_t ws_size,
                              hipStream_t stream) {
    const float* x  = (const float*)d_in[0];
    const float* Wq = (const float*)d_in[1];
    const float* Wk = (const float*)d_in[2];
    const float* Wv = (const float*)d_in[3];
    const float* Wo = (const float*)d_in[4];
    const float* bo = (const float*)d_in[5];
    float* out = (float*)d_out;

    char* ws = (char*)d_ws;
    __bf16* xb  = (__bf16*)(ws);                                  // 12,582,912
    __bf16* wt  = (__bf16*)(ws + 12582912);                       //  2,359,296
    __bf16* wot = (__bf16*)(ws + 12582912 + 2359296);             //    786,432
    char*   p0  = ws + 12582912 + 2359296 + 786432;               // 15,728,640
    __bf16* qw  = (__bf16*)(p0);                                  //  8,388,608
    __bf16* kw  = (__bf16*)(p0 + 8388608);
    __bf16* vtw = (__bf16*)(p0 + 2 * (size_t)8388608);
    __bf16* obf = (__bf16*)(p0 + 3 * (size_t)8388608);
    // total ws use: 49,283,072 bytes

    cvt_x_kernel<<<6144, 256, 0, stream>>>(x, xb, MROWS_ * DIM_ / 4);
    transpose_w_kernel<<<384, 256, 0, stream>>>(Wq, Wk, Wv, Wo, wt, wot);
    qkv_gemm_kernel<<<768, 256, 0, stream>>>(xb, wt, qw, kw, vtw);
    attn_kernel<<<512, 256, 0, stream>>>(qw, kw, vtw, obf);
    out_gemm_kernel<<<384, 256, 0, stream>>>(obf, wot, bo, out);
}

// Round 12
// 125.531 us; speedup vs baseline: 1.7152x; 1.0184x over previous
//
#include <hip/hip_runtime.h>
#include <hip/hip_bf16.h>

// Problem constants
#define B_   2
#define N_   4096
#define DIM_ 768
#define H_   8
#define MROWS_ 8192   // B_*N_

typedef __bf16 bf16x8 __attribute__((ext_vector_type(8)));
typedef __bf16 bf16x4 __attribute__((ext_vector_type(4)));
typedef float  f32x4  __attribute__((ext_vector_type(4)));

static __device__ __forceinline__ f32x4 mfma16(bf16x8 a, bf16x8 b, f32x4 c) {
    return __builtin_amdgcn_mfma_f32_16x16x32_bf16(a, b, c, 0, 0, 0);
}

// async global->LDS, 16B per lane. LDS dst is wave-uniform base + lane*16.
#define GLDS16(g, l) \
    __builtin_amdgcn_global_load_lds((const __attribute__((address_space(1))) void*)(g), \
                                     (__attribute__((address_space(3))) void*)(l), 16, 0, 0)

// ---------------------------------------------------------------------------
// Kernel 1: x (fp32) -> xb (bf16), vectorized 4/thread
__global__ void cvt_x_kernel(const float* __restrict__ x, __bf16* __restrict__ xb, int n4) {
    int i = blockIdx.x * blockDim.x + threadIdx.x;
    if (i >= n4) return;
    float4 f = reinterpret_cast<const float4*>(x)[i];
    bf16x4 o;
    o[0] = (__bf16)f.x; o[1] = (__bf16)f.y; o[2] = (__bf16)f.z; o[3] = (__bf16)f.w;
    reinterpret_cast<bf16x4*>(xb)[i] = o;
}

// ---------------------------------------------------------------------------
// Kernel 2: LDS-tiled 64x64 transpose of weights -> bf16.
__global__ __launch_bounds__(256) void transpose_w_kernel(const float* __restrict__ Wq,
                                                          const float* __restrict__ Wk,
                                                          const float* __restrict__ Wv,
                                                          const float* __restrict__ Wo,
                                                          __bf16* __restrict__ wt,
                                                          __bf16* __restrict__ wot) {
    __shared__ float tile[64][65];
    const int bix = blockIdx.x;
    const float* src;
    int src_ld, rbase, cbase, dst_ld, drow, dcol;
    __bf16* dst;
    if (bix < 288) {                       // Wq/Wk/Wv: [768][512]
        int m = bix / 96, t = bix - m * 96;
        int tr = t >> 3, tc = t & 7;
        src = (m == 0) ? Wq : ((m == 1) ? Wk : Wv);
        src_ld = 512; rbase = tr * 64; cbase = tc * 64;
        dst = wt; dst_ld = 768; drow = m * 512 + tc * 64; dcol = tr * 64;
    } else {                               // Wo: [512][768]
        int t = bix - 288;
        int tr = t / 12, tc = t - tr * 12;
        src = Wo; src_ld = 768; rbase = tr * 64; cbase = tc * 64;
        dst = wot; dst_ld = 512; drow = tc * 64; dcol = tr * 64;
    }
#pragma unroll
    for (int kk = 0; kk < 4; ++kk) {
        int idx = threadIdx.x + kk * 256;
        int r = idx >> 4, c = (idx & 15) << 2;
        float4 f = *reinterpret_cast<const float4*>(&src[(size_t)(rbase + r) * src_ld + cbase + c]);
        tile[r][c] = f.x; tile[r][c + 1] = f.y; tile[r][c + 2] = f.z; tile[r][c + 3] = f.w;
    }
    __syncthreads();
#pragma unroll
    for (int kk = 0; kk < 4; ++kk) {
        int idx = threadIdx.x + kk * 256;
        int r = idx >> 4, c = (idx & 15) << 2;
        bf16x4 ov;
        ov[0] = (__bf16)tile[c][r];     ov[1] = (__bf16)tile[c + 1][r];
        ov[2] = (__bf16)tile[c + 2][r]; ov[3] = (__bf16)tile[c + 3][r];
        *reinterpret_cast<bf16x4*>(&dst[(size_t)(drow + r) * dst_ld + dcol + c]) = ov;
    }
}

// ---------------------------------------------------------------------------
// m97-structure GEMM main loop: 128x128 tile, BK=32, 4 waves (2x2 of 64x64),
// global_load_lds(16B) double-buffered staging, 2-phase pipeline.
template<int KSTEPS>
__device__ __forceinline__ void gemm_tile_main(const __bf16* __restrict__ A, const int lda,
                                               const int arow0,
                                               const __bf16* __restrict__ Bt, const int ldb,
                                               const int bcol0,
                                               __bf16* __restrict__ abuf,
                                               __bf16* __restrict__ bbuf,
                                               f32x4 (&acc)[4][4]) {
    const int lane = threadIdx.x & 63, wave = threadIdx.x >> 6;
    const int lr = lane & 15, lg = lane >> 4;
    const int wr = wave >> 1, wc = wave & 1;

    const int cid0 = wave * 128 + lane;
    const int cid1 = cid0 + 64;
    const __bf16* sA0 = A  + (size_t)(arow0 + (cid0 >> 2)) * lda + (cid0 & 3) * 8;
    const __bf16* sA1 = A  + (size_t)(arow0 + (cid1 >> 2)) * lda + (cid1 & 3) * 8;
    const __bf16* sB0 = Bt + (size_t)(bcol0 + (cid0 >> 2)) * ldb + (cid0 & 3) * 8;
    const __bf16* sB1 = Bt + (size_t)(bcol0 + (cid1 >> 2)) * ldb + (cid1 & 3) * 8;

    auto stage = [&](int buf, int ks) {
        __bf16* da = abuf + buf * 4096 + wave * 1024;
        __bf16* db = bbuf + buf * 4096 + wave * 1024;
        GLDS16(sA0 + ks * 32, da);
        GLDS16(sA1 + ks * 32, da + 512);
        GLDS16(sB0 + ks * 32, db);
        GLDS16(sB1 + ks * 32, db + 512);
    };

    stage(0, 0);
    asm volatile("s_waitcnt vmcnt(0)" ::: "memory");
    __syncthreads();

    const int ar_off = (wr * 64 + lr) * 32 + lg * 8;
    const int br_off = (wc * 64 + lr) * 32 + lg * 8;

    int buf = 0;
    for (int ks = 0; ks < KSTEPS; ++ks) {
        if (ks + 1 < KSTEPS) stage(buf ^ 1, ks + 1);
        const __bf16* ab = abuf + buf * 4096 + ar_off;
        const __bf16* bb = bbuf + buf * 4096 + br_off;
        bf16x8 af[4], bfr[4];
#pragma unroll
        for (int m = 0; m < 4; ++m) af[m] = *reinterpret_cast<const bf16x8*>(ab + m * 512);
#pragma unroll
        for (int n = 0; n < 4; ++n) bfr[n] = *reinterpret_cast<const bf16x8*>(bb + n * 512);
#pragma unroll
        for (int m = 0; m < 4; ++m)
#pragma unroll
            for (int n = 0; n < 4; ++n)
                acc[m][n] = mfma16(af[m], bfr[n], acc[m][n]);
        asm volatile("s_waitcnt vmcnt(0)" ::: "memory");
        __syncthreads();
        buf ^= 1;
    }
}

// ---------------------------------------------------------------------------
// Kernel 3: QKV projection GEMM. 768 blocks (XCD-chunked).
// Q pre-scaled by 0.125*log2(e) (attention uses exp2). V transposed [B,H,64,N].
__global__ __launch_bounds__(256) void qkv_gemm_kernel(const __bf16* __restrict__ xb,
                                                       const __bf16* __restrict__ wt,
                                                       __bf16* __restrict__ q,
                                                       __bf16* __restrict__ k,
                                                       __bf16* __restrict__ vt) {
    __shared__ __align__(16) __bf16 abuf[2 * 4096];
    __shared__ __align__(16) __bf16 bbuf[2 * 4096];

    const int bid = blockIdx.x;
    const int vb = (bid & 7) * 96 + (bid >> 3);
    const int by = vb % 12, bx = vb / 12;

    f32x4 acc[4][4] = {};
    gemm_tile_main<24>(xb, 768, bx * 128, wt, 768, by * 128, abuf, bbuf, acc);

    const int lane = threadIdx.x & 63, wave = threadIdx.x >> 6;
    const int lr = lane & 15, lg = lane >> 4;
    const int wr = wave >> 1, wc = wave & 1;
    const int bi = (bx * 128) >> 12;
    const int nbase = (bx * 128) & 4095;

    const float QSCALE = 0.125f * 1.44269504089f;   // fold log2(e): softmax uses exp2

#pragma unroll
    for (int n = 0; n < 4; ++n) {
        const int col0 = by * 128 + wc * 64 + n * 16;
        const int mtx = col0 >> 9;
        const int h   = (col0 >> 6) & 7;
        const int d0  = (col0 & 63) + lr;
        const size_t hb = (size_t)(bi * 8 + h);
#pragma unroll
        for (int m = 0; m < 4; ++m) {
            const int nn = nbase + wr * 64 + m * 16 + lg * 4;
            if (mtx == 0) {
#pragma unroll
                for (int r = 0; r < 4; ++r)
                    q[(hb * 4096 + nn + r) * 64 + d0] = (__bf16)(acc[m][n][r] * QSCALE);
            } else if (mtx == 1) {
#pragma unroll
                for (int r = 0; r < 4; ++r)
                    k[(hb * 4096 + nn + r) * 64 + d0] = (__bf16)acc[m][n][r];
            } else {
                bf16x4 ov;
#pragma unroll
                for (int r = 0; r < 4; ++r) ov[r] = (__bf16)acc[m][n][r];
                *reinterpret_cast<bf16x4*>(&vt[(hb * 64 + d0) * 4096 + nn]) = ov;
            }
        }
    }
}

// ---------------------------------------------------------------------------
// Kernel 4: flash attention, 8 waves x (32q x 32k) -> 4 waves/SIMD with the
// SAME per-CU LDS/HBM traffic as round 11 (the occupancy lever without the
// traffic penalty). 512 blocks (XCD-chunked), 512 threads.
// Wave = (qg = w>>1 in [0,4), kh = w&1). sigma-permuted K staging keeps P
// in-register; wave kh reads s-slot groups {kh, kh+2}; V chunk kc=kh.
// Waves 0-3 stage K (2 GLDS16), waves 4-7 stage V. End: kh=1 partials via LDS.
__global__ __launch_bounds__(512, 4) void attn_kernel(const __bf16* __restrict__ q,
                                                      const __bf16* __restrict__ k,
                                                      const __bf16* __restrict__ vt,
                                                      __bf16* __restrict__ o) {
    const int lane = threadIdx.x & 63, wave = threadIdx.x >> 6;
    const int lr = lane & 15, lg = lane >> 4;
    const int qg = wave >> 1, kh = wave & 1;

    const int bid  = blockIdx.x;
    const int vbid = (bid & 7) * 64 + (bid >> 3);
    const int qtile = vbid & 31;
    const int bh    = vbid >> 5;
    const int qbase = qtile * 128 + qg * 32;

    const __bf16* Qh = q  + (size_t)bh * N_ * 64;
    const __bf16* Kh = k  + (size_t)bh * N_ * 64;
    const __bf16* Vh = vt + (size_t)bh * 64 * N_;

    __shared__ __align__(16) char smem[32768];
    __bf16* kb0 = (__bf16*)smem;            // kbuf[2][64][64], 16KB
    __bf16* vb0 = (__bf16*)(smem + 16384);  // vbuf[2][64][64], 16KB

    const int l8 = lane >> 3, l7 = lane & 7;
    const int swz8 = (l7 ^ l8) * 8;

    // K-stager (waves 0-3): rows [wave*16, +16) as 2 chunks of 8 rows,
    // source row sigma(i), chunk-swizzled.
    int ksrc[2];
#pragma unroll
    for (int c = 0; c < 2; ++c) {
        int i = wave * 16 + c * 8 + l8;
        int sig = ((i >> 4) & 1) * 32 + ((i >> 2) & 3) * 8 + ((i >> 5) & 1) * 4 + (i & 3);
        ksrc[c] = sig * 64 + swz8;
    }

    auto stageK = [&](int buf, int jt) {    // waves 0-3
        if (wave < 4) {
            const __bf16* srcb = Kh + (size_t)jt * 4096;
            __bf16* dst = kb0 + buf * 4096 + wave * 1024;
            GLDS16(srcb + ksrc[0], dst);
            GLDS16(srcb + ksrc[1], dst + 512);
        }
    };
    auto stageV = [&](int buf, int jt) {    // waves 4-7: d-rows [w2*16, +16)
        if (wave >= 4) {
            const int w2 = wave - 4;
            const __bf16* src = Vh + (size_t)(w2 * 16 + l8) * 4096 + jt * 64 + swz8;
            __bf16* dst = vb0 + buf * 4096 + w2 * 1024;
            GLDS16(src, dst);
            GLDS16(src + (size_t)8 * 4096, dst + 512);
        }
    };

    bf16x8 qf[2][2];
#pragma unroll
    for (int f = 0; f < 2; ++f)
#pragma unroll
        for (int kc = 0; kc < 2; ++kc)
            qf[f][kc] = *reinterpret_cast<const bf16x8*>(
                Qh + (size_t)(qbase + f * 16 + lr) * 64 + kc * 32 + lg * 8);

    f32x4 acc[2][4] = {};
    f32x4 accl[2] = {};
    bf16x8 vones;
#pragma unroll
    for (int t = 0; t < 8; ++t) vones[t] = (__bf16)1.0f;

    f32x4 s[2][2];      // 32q x 32k logits (s-slot groups kh, kh+2)
    bf16x8 pk[2];       // previous tile's P, PV A-fragments

    auto QK = [&](const __bf16* kb_) {
        const char* kb = (const char*)kb_;
        __builtin_amdgcn_s_setprio(1);
#pragma unroll
        for (int kc = 0; kc < 2; ++kc) {
#pragma unroll
            for (int c2 = 0; c2 < 2; ++c2) {
                const int row = (kh + 2 * c2) * 16 + lr;
                bf16x8 bk = *reinterpret_cast<const bf16x8*>(
                    kb + row * 128 + (((kc * 4 + lg) ^ (lr & 7)) << 4));
#pragma unroll
                for (int f = 0; f < 2; ++f) {
                    if (kc == 0) s[f][c2] = mfma16(bk, qf[f][0], {});
                    else         s[f][c2] = mfma16(bk, qf[f][1], s[f][c2]);
                }
            }
        }
        __builtin_amdgcn_s_setprio(0);
    };
    auto EXP = [&]() {   // s -> pk; partial lsum via matrix pipe
#pragma unroll
        for (int f = 0; f < 2; ++f) {
#pragma unroll
            for (int t = 0; t < 8; ++t)
                pk[f][t] = (__bf16)__builtin_amdgcn_exp2f(s[f][t >> 2][t & 3]);
            accl[f] = mfma16(pk[f], vones, accl[f]);
        }
    };
    auto PV = [&](const __bf16* vb_) {   // consumes pk; V chunk kc = kh
        const char* vb = (const char*)vb_;
        __builtin_amdgcn_s_setprio(1);
#pragma unroll
        for (int cbv = 0; cbv < 4; ++cbv) {
            const int row = cbv * 16 + lr;
            bf16x8 bv = *reinterpret_cast<const bf16x8*>(
                vb + row * 128 + (((kh * 4 + lg) ^ (lr & 7)) << 4));
#pragma unroll
            for (int f = 0; f < 2; ++f)
                acc[f][cbv] = mfma16(pk[f], bv, acc[f][cbv]);
        }
        __builtin_amdgcn_s_setprio(0);
    };

    // ---- prologue
    stageK(0, 0);
    asm volatile("s_waitcnt vmcnt(0)" ::: "memory");
    __syncthreads();

    // ---- iter 0
    stageK(1, 1);
    stageV(0, 0);
    QK(kb0);             // tile 0 from kbuf[0]
    EXP();               // pk = P(0)
    asm volatile("s_waitcnt vmcnt(0)" ::: "memory");
    __syncthreads();

    // ---- iters 1..62
    for (int jt = 1; jt < 63; ++jt) {
        stageK((jt + 1) & 1, jt + 1);
        stageV(jt & 1, jt);
        QK(kb0 + (jt & 1) * 4096);          // tile jt
        PV(vb0 + ((jt - 1) & 1) * 4096);    // tile jt-1
        EXP();                              // pk = P(jt)
        asm volatile("s_waitcnt vmcnt(0)" ::: "memory");
        __syncthreads();
    }

    // ---- iter 63 (no more K)
    stageV(1, 63);
    QK(kb0 + 4096);      // tile 63 from kbuf[1]
    PV(vb0);             // tile 62 from vbuf[0]
    EXP();               // pk = P(63)
    asm volatile("s_waitcnt vmcnt(0)" ::: "memory");
    __syncthreads();

    // ---- final PV(63) from vbuf[1]
    PV(vb0 + 4096);
    __syncthreads();     // all waves done reading K/V tiles

    // ---- cross-wave combine: kh=1 writes partials (acc bf16 16KB-region,
    // lsum f32 8KB-region), kh=0 combines and writes output.
    char* exa = smem + qg * 4096;            // acc partials: 64 lanes x 64B
    char* exl = smem + 16384 + qg * 2048;    // lsum partials: 64 lanes x 32B
    if (kh == 1) {
#pragma unroll
        for (int f = 0; f < 2; ++f) {
#pragma unroll
            for (int cbv = 0; cbv < 4; ++cbv) {
                bf16x4 p4;
#pragma unroll
                for (int r = 0; r < 4; ++r) p4[r] = (__bf16)acc[f][cbv][r];
                *reinterpret_cast<bf16x4*>(exa + lane * 64 + (f * 4 + cbv) * 8) = p4;
            }
            *reinterpret_cast<f32x4*>(exl + lane * 32 + f * 16) = accl[f];
        }
    }
    __syncthreads();

    if (kh == 0) {
        const int b = bh >> 3, h = bh & 7;
#pragma unroll
        for (int f = 0; f < 2; ++f) {
            f32x4 lp = *reinterpret_cast<const f32x4*>(exl + lane * 32 + f * 16);
            f32x4 inv;
#pragma unroll
            for (int r = 0; r < 4; ++r) inv[r] = 1.f / (accl[f][r] + lp[r]);
#pragma unroll
            for (int cbv = 0; cbv < 4; ++cbv) {
                bf16x4 ap = *reinterpret_cast<const bf16x4*>(exa + lane * 64 + (f * 4 + cbv) * 8);
#pragma unroll
                for (int r = 0; r < 4; ++r) {
                    const int row = b * N_ + qbase + f * 16 + lg * 4 + r;
                    o[(size_t)row * 512 + h * 64 + cbv * 16 + lr] =
                        (__bf16)((acc[f][cbv][r] + (float)ap[r]) * inv[r]);
                }
            }
        }
    }
}

// ---------------------------------------------------------------------------
// Kernel 5: output projection GEMM. 384 blocks. K=512.
__global__ __launch_bounds__(256) void out_gemm_kernel(const __bf16* __restrict__ ob,
                                                       const __bf16* __restrict__ wot,
                                                       const float* __restrict__ bo,
                                                       float* __restrict__ out) {
    __shared__ __align__(16) __bf16 abuf[2 * 4096];
    __shared__ __align__(16) __bf16 bbuf[2 * 4096];

    const int bid = blockIdx.x;
    const int vb = (bid & 7) * 48 + (bid >> 3);
    const int by = vb % 6, bx = vb / 6;

    f32x4 acc[4][4] = {};
    gemm_tile_main<16>(ob, 512, bx * 128, wot, 512, by * 128, abuf, bbuf, acc);

    const int lane = threadIdx.x & 63, wave = threadIdx.x >> 6;
    const int lr = lane & 15, lg = lane >> 4;
    const int wr = wave >> 1, wc = wave & 1;

#pragma unroll
    for (int n = 0; n < 4; ++n) {
        const int col = by * 128 + wc * 64 + n * 16 + lr;
        const float bias = bo[col];
#pragma unroll
        for (int m = 0; m < 4; ++m) {
            const int row0 = bx * 128 + wr * 64 + m * 16 + lg * 4;
#pragma unroll
            for (int r = 0; r < 4; ++r)
                out[(size_t)(row0 + r) * 768 + col] = acc[m][n][r] + bias;
        }
    }
}

// ---------------------------------------------------------------------------
extern "C" void kernel_launch(void* const* d_in, const int* in_sizes, int n_in,
                              void* d_out, int out_size, void* d_ws, size_t ws_size,
                              hipStream_t stream) {
    const float* x  = (const float*)d_in[0];
    const float* Wq = (const float*)d_in[1];
    const float* Wk = (const float*)d_in[2];
    const float* Wv = (const float*)d_in[3];
    const float* Wo = (const float*)d_in[4];
    const float* bo = (const float*)d_in[5];
    float* out = (float*)d_out;

    char* ws = (char*)d_ws;
    __bf16* xb  = (__bf16*)(ws);                                  // 12,582,912
    __bf16* wt  = (__bf16*)(ws + 12582912);                       //  2,359,296
    __bf16* wot = (__bf16*)(ws + 12582912 + 2359296);             //    786,432
    char*   p0  = ws + 12582912 + 2359296 + 786432;               // 15,728,640
    __bf16* qw  = (__bf16*)(p0);                                  //  8,388,608
    __bf16* kw  = (__bf16*)(p0 + 8388608);
    __bf16* vtw = (__bf16*)(p0 + 2 * (size_t)8388608);
    __bf16* obf = (__bf16*)(p0 + 3 * (size_t)8388608);
    // total ws use: 49,283,072 bytes

    cvt_x_kernel<<<6144, 256, 0, stream>>>(x, xb, MROWS_ * DIM_ / 4);
    transpose_w_kernel<<<384, 256, 0, stream>>>(Wq, Wk, Wv, Wo, wt, wot);
    qkv_gemm_kernel<<<768, 256, 0, stream>>>(xb, wt, qw, kw, vtw);
    attn_kernel<<<512, 512, 0, stream>>>(qw, kw, vtw, obf);
    out_gemm_kernel<<<384, 256, 0, stream>>>(obf, wot, bo, out);
}